// Round 21
// baseline (71.721 us; speedup 1.0000x reference)
//
#include <hip/hip_runtime.h>
#include <hip/hip_bf16.h>

// B=128, CIN=3, H=W=32, C1=64, C2=256, NUM_CLASSES=1000
// K_CONV=48, K_FC=12451 >= 48*256 => FC reduces exactly to the 48 selected
// channels' pooled features. Slot order = rank order; FC sum order-invariant.
// R21: (1) k2 latency-chain fix: unroll rank(x16)/red(x8) loops -- R14 counters
// (occ 2.3%, VALU 4%) imply serial ~120cy LDS chains dominate its 9us.
// (2) k4 Ksplit 32->64 (2048 blocks, 8/CU -> more HBM streams); k5 sums 64.

#define NSEL 48
#define NCLS 1000

__device__ __forceinline__ unsigned short f2bf(float x) {
  unsigned u = __builtin_bit_cast(unsigned, x);
  u += 0x7fffu + ((u >> 16) & 1u);  // RNE (finite inputs)
  return (unsigned short)(u >> 16);
}

__device__ __forceinline__ float bf2f(unsigned short u) {
  return __builtin_bit_cast(float, (unsigned)u << 16);
}

__device__ __forceinline__ void gl_lds16(const void* g, void* l) {
  __builtin_amdgcn_global_load_lds(
      (const __attribute__((address_space(1))) void*)g,
      (__attribute__((address_space(3))) void*)l, 16, 0, 0);
}

using sh8 = __attribute__((ext_vector_type(8))) short;
using f4  = __attribute__((ext_vector_type(4))) float;

// ---------------- K1: conv1 via MFMA (M=256pix, N=64oc, K=27pad32) ----------------
__global__ __launch_bounds__(256) void k1_conv1(
    const float* __restrict__ x0, const float* __restrict__ w1,
    const float* __restrict__ b1, unsigned short* __restrict__ x1,
    float* __restrict__ part2) {
  const int b = blockIdx.x, quarter = blockIdx.y;
  const int t = threadIdx.x;
  const int w = t >> 6, l = t & 63;
  const int ln15 = l & 15, oct = l >> 4;
  const int r0 = quarter * 8;

  __shared__ __align__(16) char smem[36864];
  __shared__ float wred[64 * 4];
  float* xs = (float*)(smem + 20480);
  short* w1t = (short*)(smem + 24320);

  for (int q = 0; q < 4; ++q) {
    const int id = q * 256 + t;
    if (id < 960) {
      const int ic = id / 320;
      const int rem = id - ic * 320;
      const int row = rem >> 5, col = rem & 31;
      const int gr = r0 - 1 + row;
      xs[id] = ((unsigned)gr < 32u)
                   ? x0[((size_t)b * 3 + ic) * 1024 + gr * 32 + col] : 0.f;
    }
  }
#pragma unroll
  for (int j = 0; j < 8; ++j) {
    const int e = j * 256 + t;
    const int oc = e & 63, k = e >> 6;
    const float v = (k < 27) ? w1[oc * 27 + k] : 0.f;
    w1t[((k >> 3) * 64 + oc) * 8 + (k & 7)] = f2bf(v);
  }
  float bias[4];
#pragma unroll
  for (int nt = 0; nt < 4; ++nt) bias[nt] = b1[nt * 16 + ln15];
  __syncthreads();

  {
    const int lr = t >> 5, pc = t & 31;
    int* prow = (int*)(smem + t * 80);
    unsigned pk2[16];
#pragma unroll
    for (int k = 0; k < 32; k += 2) {
      float v[2];
#pragma unroll
      for (int d = 0; d < 2; ++d) {
        const int kk = k + d;
        if (kk < 27) {
          const int ic = kk / 9, r9 = kk - ic * 9;
          const int kr = r9 / 3, kc = r9 - kr * 3;
          const int cc = pc + kc - 1;
          v[d] = ((unsigned)cc < 32u) ? xs[ic * 320 + (lr + kr) * 32 + cc] : 0.f;
        } else v[d] = 0.f;
      }
      pk2[k >> 1] = f2bf(v[0]) | ((unsigned)f2bf(v[1]) << 16);
    }
#pragma unroll
    for (int k2 = 0; k2 < 16; ++k2) prow[k2] = pk2[k2];
  }
  __syncthreads();

  sh8 afr[4], bfr[4];
#pragma unroll
  for (int i = 0; i < 4; ++i)
    afr[i] = *reinterpret_cast<const sh8*>(
        smem + (w * 64 + i * 16 + ln15) * 80 + oct * 16);
#pragma unroll
  for (int nt = 0; nt < 4; ++nt)
    bfr[nt] = *reinterpret_cast<const sh8*>(
        smem + 24320 + (oct * 64 + nt * 16 + ln15) * 16);
  __syncthreads();

  f4 acc[4][4];
#pragma unroll
  for (int i = 0; i < 4; ++i)
#pragma unroll
    for (int nt = 0; nt < 4; ++nt) {
      const float bv = bias[nt];
      acc[i][nt] = f4{bv, bv, bv, bv};
    }
#pragma unroll
  for (int i = 0; i < 4; ++i)
#pragma unroll
    for (int nt = 0; nt < 4; ++nt)
      acc[i][nt] = __builtin_amdgcn_mfma_f32_16x16x32_bf16(
          afr[i], bfr[nt], acc[i][nt], 0, 0, 0);

  short* po = (short*)smem;
  float wsum[4] = {0.f, 0.f, 0.f, 0.f};
#pragma unroll
  for (int i = 0; i < 4; ++i)
#pragma unroll
    for (int nt = 0; nt < 4; ++nt) {
      const f4 v = acc[i][nt];
#pragma unroll
      for (int r = 0; r < 4; ++r) {
        float x = v[r] > 0.f ? v[r] : 0.f;
        wsum[nt] += x;
        po[(w * 64 + i * 16 + oct * 4 + r) * 72 + nt * 16 + ln15] = f2bf(x);
      }
    }
#pragma unroll
  for (int nt = 0; nt < 4; ++nt) {
    float s = wsum[nt];
    s += __shfl_xor(s, 16);
    s += __shfl_xor(s, 32);
    if (l < 16) wred[(nt * 16 + ln15) * 4 + w] = s;
  }
  __syncthreads();

  {
    const int4* src = reinterpret_cast<const int4*>(smem + t * 144);
    int4* dst = reinterpret_cast<int4*>(x1) +
                ((size_t)b * 1024 + quarter * 256 + t) * 8;
#pragma unroll
    for (int j = 0; j < 8; ++j) dst[j] = src[j];
  }
  if (t < 64) {
    const float s = wred[t * 4] + wred[t * 4 + 1] + wred[t * 4 + 2] + wred[t * 4 + 3];
    part2[((size_t)quarter * 64 + t) * 128 + b] = s;
  }
}

// ---------------- K2: selection (redundant per block) + weight prep (block j) -----
__global__ __launch_bounds__(256) void k2_selprep(
    const float* __restrict__ part2, const float* __restrict__ gate_w,
    const float* __restrict__ w2, const float* __restrict__ b2,
    int* __restrict__ sel, unsigned short* __restrict__ w2t,
    float* __restrict__ b2s) {
  const int t = threadIdx.x;
  const int j = blockIdx.x;  // slot = rank
  __shared__ float gw[256 * 65];
  __shared__ float red[64 * 33];
  __shared__ float sig[64];
  __shared__ float sc[256];
  __shared__ int pick;

  {  // stage gate_w coalesced into padded LDS
    const float4* gv = reinterpret_cast<const float4*>(gate_w);
#pragma unroll
    for (int i = 0; i < 16; ++i) {
      const int f = i * 256 + t;
      const float4 v = gv[f];
      float* d = &gw[(f >> 4) * 65 + (f & 15) * 4];
      d[0] = v.x; d[1] = v.y; d[2] = v.z; d[3] = v.w;
    }
  }

  float prt[8];
#pragma unroll
  for (int k = 0; k < 8; ++k) prt[k] = 0.f;
  const float4* pv = reinterpret_cast<const float4*>(part2);
#pragma unroll
  for (int q = 0; q < 32; ++q) {
    const float4 v = pv[q * 256 + t];
    prt[q & 7] += v.x + v.y + v.z + v.w;
  }
#pragma unroll
  for (int k = 0; k < 8; ++k)
    red[(k * 8 + (t >> 5)) * 33 + (t & 31)] = prt[k];
  __syncthreads();
  if (t < 64) {
    float s = 0.f;
#pragma unroll 8
    for (int i = 0; i < 32; ++i) s += red[t * 33 + i];
    sig[t] = s * (1.0f / 131072.0f);
  }
  __syncthreads();

  {
    float lg = 0.f;
#pragma unroll 8
    for (int i = 0; i < 64; ++i) lg += gw[t * 65 + i] * sig[i];
    sc[t] = lg;  // softplus monotone -> rank by logits
  }
  __syncthreads();

  {
    const float v = sc[t];
    int r = 0;
#pragma unroll 16
    for (int i = 0; i < 256; ++i) {
      const float vi = sc[i];
      r += (vi > v) || (vi == v && i < t);
    }
    if (r == j) pick = t;
    if (j == 0 && r < NSEL) sel[r] = t;
  }
  __syncthreads();

  const int c = pick;
  if (t == 0) b2s[j] = b2[c];
  for (int id = t; id < 576; id += 256) {
    const float v = w2[(size_t)c * 576 + id];
    const int ic = id / 9;
    const int s = id - ic * 9;
    w2t[((size_t)s * 48 + j) * 64 + ic] = f2bf(v);
  }
}

// ---------------- K3: conv2 via 9-shift bf16 MFMA + bias + ReLU + maxpool ---------
__global__ __launch_bounds__(256) void k3_conv2(
    const unsigned short* __restrict__ x1, const unsigned short* __restrict__ w2t,
    const float* __restrict__ b2s, unsigned short* __restrict__ pooledt) {
  const int b = blockIdx.x, quarter = blockIdx.y;
  const int t = threadIdx.x;
  const int w = t >> 6, l = t & 63;
  const int q4 = l >> 4, ln15 = l & 15;
  __shared__ short xt[20480];

  const int r0 = quarter * 8;

  for (int q = 0; q < 10; ++q) {
    const int S = (w * 10 + q) * 64 + l;
    const int pix = S >> 3, slot = S & 7;
    const int row = pix >> 5, col = pix & 31;
    int gr = r0 - 1 + row;
    gr = gr < 0 ? 0 : (gr > 31 ? 31 : gr);
    const unsigned short* gsrc =
        x1 + ((size_t)(b * 1024 + gr * 32 + col) * 64) + (slot ^ (pix & 7)) * 8;
    gl_lds16((const void*)gsrc, (void*)&xt[(w * 10 + q) * 512]);
  }
  __syncthreads();

  f4 acc[4][3];
  const f4 fz = {0.f, 0.f, 0.f, 0.f};
#pragma unroll
  for (int i = 0; i < 4; ++i)
#pragma unroll
    for (int nt = 0; nt < 3; ++nt) acc[i][nt] = fz;

  const int w4 = w * 4;
  const sh8 zz = {0, 0, 0, 0, 0, 0, 0, 0};

#pragma unroll
  for (int kh = 0; kh < 3; ++kh)
#pragma unroll
    for (int kw = 0; kw < 3; ++kw) {
      const int sh = kh * 3 + kw;
      sh8 bf[3][2];
#pragma unroll
      for (int nt = 0; nt < 3; ++nt)
#pragma unroll
        for (int ks = 0; ks < 2; ++ks)
          bf[nt][ks] = *reinterpret_cast<const sh8*>(
              w2t + ((size_t)(sh * 48 + nt * 16 + ln15) * 64 + ks * 32 + q4 * 8));
#pragma unroll
      for (int i = 0; i < 4; ++i) {
        const int mt = w4 + i;
        const int lsr = (mt >> 1) + kh;
        const int gsr = r0 + lsr - 1;
        if ((unsigned)gsr < 32u) {
          const int w_ = (mt & 1) * 16 + ln15;
          const int cc = w_ + kw - 1;
          const bool cv = (unsigned)cc < 32u;
          int p = lsr * 32 + cc;
          p = p < 0 ? 0 : (p > 319 ? 319 : p);
#pragma unroll
          for (int ks = 0; ks < 2; ++ks) {
            sh8 af = *reinterpret_cast<const sh8*>(
                &xt[p * 64 + (((ks << 2) | q4) ^ (p & 7)) * 8]);
            af = cv ? af : zz;
            acc[i][0] = __builtin_amdgcn_mfma_f32_16x16x32_bf16(af, bf[0][ks], acc[i][0], 0, 0, 0);
            acc[i][1] = __builtin_amdgcn_mfma_f32_16x16x32_bf16(af, bf[1][ks], acc[i][1], 0, 0, 0);
            acc[i][2] = __builtin_amdgcn_mfma_f32_16x16x32_bf16(af, bf[2][ks], acc[i][2], 0, 0, 0);
          }
        }
      }
    }

  __syncthreads();

  float bias[3];
#pragma unroll
  for (int nt = 0; nt < 3; ++nt) bias[nt] = b2s[nt * 16 + ln15];

  unsigned short* ps = reinterpret_cast<unsigned short*>(xt);
#pragma unroll
  for (int a = 0; a < 2; ++a) {
#pragma unroll
    for (int nt = 0; nt < 3; ++nt) {
      const f4 A = acc[a][nt], Bv = acc[a + 2][nt];
#pragma unroll
      for (int pr = 0; pr < 2; ++pr) {
        float m = fmaxf(fmaxf(A[pr * 2], A[pr * 2 + 1]),
                        fmaxf(Bv[pr * 2], Bv[pr * 2 + 1]));
        m = fmaxf(m + bias[nt], 0.f);
        const int pl = w * 16 + a * 8 + q4 * 2 + pr;
        ps[(nt * 16 + ln15) * 64 + pl] = f2bf(m);
      }
    }
  }
  __syncthreads();

  const int4* psv = reinterpret_cast<const int4*>(xt);
  int4* po = reinterpret_cast<int4*>(pooledt);
  for (int c = t; c < 384; c += 256) {
    const int j = c >> 3, sub = c & 7;
    po[(size_t)(j * 32 + quarter * 8 + sub) * 128 + b] = psv[c];
  }
}

// ---------------- K4: bf16 MFMA GEMM partials. BM=128, BN=32, Ksplit=64 -----------
__global__ __launch_bounds__(256) void k4_fc(
    const unsigned short* __restrict__ pooledt, const float* __restrict__ fc_w,
    const int* __restrict__ sel, unsigned short* __restrict__ fcpart) {
  const int ntile = blockIdx.x;  // 0..31  (BN=32)
  const int ks = blockIdx.y;     // 0..63  (K chunk = 192 = 3 x 64k tiles)
  const int t = threadIdx.x;
  const int w = t >> 6, l = t & 63;
  const int ln15 = l & 15;

  __shared__ short Ab[2][8192];       // [ko 8][m 128][8]
  __shared__ short Bb[2][8 * 33 * 8]; // [ko 8][n pad33][8]

  f4 acc00 = {0.f, 0.f, 0.f, 0.f}, acc01 = acc00, acc10 = acc00, acc11 = acc00;

  int chs[3];
#pragma unroll
  for (int i = 0; i < 3; ++i)
    chs[i] = __builtin_amdgcn_readfirstlane(sel[(ks * 3 + i) >> 2]);

  const int n0 = ntile * 32;
  const int bn = w * 8 + (l >> 3);      // B row 0..31
  int ngb = n0 + bn; if (ngb > 999) ngb = 999;  // tail cols ignored by k5
  const float* brow = fc_w + (size_t)ngb * 65536 + (l & 7) * 8;

  const int4* pt = reinterpret_cast<const int4*>(pooledt);
  const int kb0 = ks * 24;

  int4 av[4];
  float4 bv0, bv1;

#define LOADAB(tn)                                                        \
  {                                                                       \
    _Pragma("unroll") for (int it = 0; it < 4; ++it) {                    \
      const int s = it * 256 + t;                                         \
      av[it] = pt[(kb0 + (tn) * 8 + (s >> 7)) * 128 + (s & 127)];         \
    }                                                                     \
    const float* bp = brow + chs[tn] * 256 + ((ks * 3 + (tn)) & 3) * 64;  \
    bv0 = *reinterpret_cast<const float4*>(bp);                           \
    bv1 = *reinterpret_cast<const float4*>(bp + 4);                       \
  }
#define WRITEAB(buf)                                                      \
  {                                                                       \
    _Pragma("unroll") for (int it = 0; it < 4; ++it)                      \
      *reinterpret_cast<int4*>(&Ab[buf][(it * 256 + t) * 8]) = av[it];    \
    int4 bw;                                                              \
    bw.x = f2bf(bv0.x) | ((unsigned)f2bf(bv0.y) << 16);                   \
    bw.y = f2bf(bv0.z) | ((unsigned)f2bf(bv0.w) << 16);                   \
    bw.z = f2bf(bv1.x) | ((unsigned)f2bf(bv1.y) << 16);                   \
    bw.w = f2bf(bv1.z) | ((unsigned)f2bf(bv1.w) << 16);                   \
    *reinterpret_cast<int4*>(&Bb[buf][((l & 7) * 33 + bn) * 8]) = bw;     \
  }

  LOADAB(0);
  WRITEAB(0);
  __syncthreads();

  for (int tt = 0; tt < 3; ++tt) {
    const int cur = tt & 1, nxt = cur ^ 1;
    if (tt < 2) LOADAB(tt + 1);

#pragma unroll
    for (int s2 = 0; s2 < 2; ++s2) {
      const int kg = s2 * 4 + (l >> 4);
      const int m0 = w * 32 + ln15;
      sh8 a0 = *reinterpret_cast<const sh8*>(&Ab[cur][(kg * 128 + m0) * 8]);
      sh8 a1 = *reinterpret_cast<const sh8*>(&Ab[cur][(kg * 128 + m0 + 16) * 8]);
      sh8 b0 = *reinterpret_cast<const sh8*>(&Bb[cur][(kg * 33 + ln15) * 8]);
      sh8 b1 = *reinterpret_cast<const sh8*>(&Bb[cur][(kg * 33 + 16 + ln15) * 8]);
      acc00 = __builtin_amdgcn_mfma_f32_16x16x32_bf16(a0, b0, acc00, 0, 0, 0);
      acc01 = __builtin_amdgcn_mfma_f32_16x16x32_bf16(a0, b1, acc01, 0, 0, 0);
      acc10 = __builtin_amdgcn_mfma_f32_16x16x32_bf16(a1, b0, acc10, 0, 0, 0);
      acc11 = __builtin_amdgcn_mfma_f32_16x16x32_bf16(a1, b1, acc11, 0, 0, 0);
    }

    if (tt < 2) WRITEAB(nxt);
    __syncthreads();
  }
#undef LOADAB
#undef WRITEAB

  const int r0 = (l >> 4) * 4;
#pragma unroll
  for (int fm = 0; fm < 2; ++fm)
#pragma unroll
    for (int fn = 0; fn < 2; ++fn) {
      const f4 a = fm == 0 ? (fn == 0 ? acc00 : acc01) : (fn == 0 ? acc10 : acc11);
#pragma unroll
      for (int r = 0; r < 4; ++r) {
        const int m = w * 32 + fm * 16 + r0 + r;
        const int nc = n0 + fn * 16 + ln15;
        fcpart[(((size_t)ks * 128 + m) << 10) + nc] = f2bf(a[r]);
      }
    }
}

// ---------------- K5: reduce 64 bf16 K-split partials + bias ----------------------
__global__ __launch_bounds__(256) void k5_reduce(
    const unsigned short* __restrict__ fcpart, const float* __restrict__ fc_b,
    float* __restrict__ out) {
  const int id = blockIdx.x * 256 + threadIdx.x;  // 0..127999
  const int b = id / 1000;
  const int n = id - b * 1000;
  float s = fc_b[n];
#pragma unroll
  for (int ks = 0; ks < 64; ++ks)
    s += bf2f(fcpart[(((size_t)ks * 128 + b) << 10) + n]);
  out[id] = s;
}

extern "C" void kernel_launch(void* const* d_in, const int* in_sizes, int n_in,
                              void* d_out, int out_size, void* d_ws, size_t ws_size,
                              hipStream_t stream) {
  (void)in_sizes; (void)n_in; (void)out_size; (void)ws_size;
  const float* x0     = (const float*)d_in[0];
  const float* w1     = (const float*)d_in[1];
  const float* b1     = (const float*)d_in[2];
  const float* gate_w = (const float*)d_in[3];
  const float* w2     = (const float*)d_in[4];
  const float* b2     = (const float*)d_in[5];
  const float* fc_w   = (const float*)d_in[6];
  const float* fc_b   = (const float*)d_in[7];
  float* out = (float*)d_out;

  char* ws = (char*)d_ws;
  unsigned short* x1      = (unsigned short*)(ws);             // 16,777,216 B
  unsigned short* pooledt = (unsigned short*)(ws + 16777216);  //  3,145,728 B
  float*          part2   = (float*)(ws + 19922944);           //    131,072 B
  int*            sel     = (int*)  (ws + 20054016);           //        256 B
  unsigned short* w2t     = (unsigned short*)(ws + 20054272);  //     55,296 B
  float*          b2s     = (float*)(ws + 20109568);           //        768 B
  unsigned short* fcpart  = (unsigned short*)(ws + 20110336);  // 16,777,216 B

  hipLaunchKernelGGL(k1_conv1, dim3(128, 4), dim3(256), 0, stream, x0, w1, b1, x1, part2);
  hipLaunchKernelGGL(k2_selprep, dim3(48), dim3(256), 0, stream, part2, gate_w, w2, b2, sel, w2t, b2s);
  hipLaunchKernelGGL(k3_conv2, dim3(128, 4), dim3(256), 0, stream, x1, w2t, b2s, pooledt);
  hipLaunchKernelGGL(k4_fc, dim3(32, 64), dim3(256), 0, stream, pooledt, fc_w, sel, fcpart);
  hipLaunchKernelGGL(k5_reduce, dim3(500), dim3(256), 0, stream, fcpart, fc_b, out);
}

// Round 22
// 69.198 us; speedup vs baseline: 1.0365x; 1.0365x over previous
//
#include <hip/hip_runtime.h>
#include <hip/hip_bf16.h>

// B=128, CIN=3, H=W=32, C1=64, C2=256, NUM_CLASSES=1000
// K_CONV=48, K_FC=12451 >= 48*256 => FC reduces exactly to the 48 selected
// channels' pooled features. Slot order = rank order; FC sum order-invariant.
// FINAL LOCK-IN (R20 config, best measured 70.1us): k1 MFMA implicit-GEMM
// conv1; k2 48-block selprep with LDS-staged gate_w; k3 9-shift MFMA conv2
// +pool; k4 bf16-MFMA FC Ksplit=32, coalesced B, bf16 partials; k5 reduce.
// R19-21 established: remaining gap is dispatch/latency structural (~25us
// fixed + latency-bound small kernels); all fusion mechanisms measured worse.

#define NSEL 48
#define NCLS 1000

__device__ __forceinline__ unsigned short f2bf(float x) {
  unsigned u = __builtin_bit_cast(unsigned, x);
  u += 0x7fffu + ((u >> 16) & 1u);  // RNE (finite inputs)
  return (unsigned short)(u >> 16);
}

__device__ __forceinline__ float bf2f(unsigned short u) {
  return __builtin_bit_cast(float, (unsigned)u << 16);
}

__device__ __forceinline__ void gl_lds16(const void* g, void* l) {
  __builtin_amdgcn_global_load_lds(
      (const __attribute__((address_space(1))) void*)g,
      (__attribute__((address_space(3))) void*)l, 16, 0, 0);
}

using sh8 = __attribute__((ext_vector_type(8))) short;
using f4  = __attribute__((ext_vector_type(4))) float;

// ---------------- K1: conv1 via MFMA (M=256pix, N=64oc, K=27pad32) ----------------
__global__ __launch_bounds__(256) void k1_conv1(
    const float* __restrict__ x0, const float* __restrict__ w1,
    const float* __restrict__ b1, unsigned short* __restrict__ x1,
    float* __restrict__ part2) {
  const int b = blockIdx.x, quarter = blockIdx.y;
  const int t = threadIdx.x;
  const int w = t >> 6, l = t & 63;
  const int ln15 = l & 15, oct = l >> 4;
  const int r0 = quarter * 8;

  __shared__ __align__(16) char smem[36864];
  __shared__ float wred[64 * 4];
  float* xs = (float*)(smem + 20480);
  short* w1t = (short*)(smem + 24320);

  for (int q = 0; q < 4; ++q) {
    const int id = q * 256 + t;
    if (id < 960) {
      const int ic = id / 320;
      const int rem = id - ic * 320;
      const int row = rem >> 5, col = rem & 31;
      const int gr = r0 - 1 + row;
      xs[id] = ((unsigned)gr < 32u)
                   ? x0[((size_t)b * 3 + ic) * 1024 + gr * 32 + col] : 0.f;
    }
  }
#pragma unroll
  for (int j = 0; j < 8; ++j) {
    const int e = j * 256 + t;
    const int oc = e & 63, k = e >> 6;
    const float v = (k < 27) ? w1[oc * 27 + k] : 0.f;
    w1t[((k >> 3) * 64 + oc) * 8 + (k & 7)] = f2bf(v);
  }
  float bias[4];
#pragma unroll
  for (int nt = 0; nt < 4; ++nt) bias[nt] = b1[nt * 16 + ln15];
  __syncthreads();

  {
    const int lr = t >> 5, pc = t & 31;
    int* prow = (int*)(smem + t * 80);
    unsigned pk2[16];
#pragma unroll
    for (int k = 0; k < 32; k += 2) {
      float v[2];
#pragma unroll
      for (int d = 0; d < 2; ++d) {
        const int kk = k + d;
        if (kk < 27) {
          const int ic = kk / 9, r9 = kk - ic * 9;
          const int kr = r9 / 3, kc = r9 - kr * 3;
          const int cc = pc + kc - 1;
          v[d] = ((unsigned)cc < 32u) ? xs[ic * 320 + (lr + kr) * 32 + cc] : 0.f;
        } else v[d] = 0.f;
      }
      pk2[k >> 1] = f2bf(v[0]) | ((unsigned)f2bf(v[1]) << 16);
    }
#pragma unroll
    for (int k2 = 0; k2 < 16; ++k2) prow[k2] = pk2[k2];
  }
  __syncthreads();

  sh8 afr[4], bfr[4];
#pragma unroll
  for (int i = 0; i < 4; ++i)
    afr[i] = *reinterpret_cast<const sh8*>(
        smem + (w * 64 + i * 16 + ln15) * 80 + oct * 16);
#pragma unroll
  for (int nt = 0; nt < 4; ++nt)
    bfr[nt] = *reinterpret_cast<const sh8*>(
        smem + 24320 + (oct * 64 + nt * 16 + ln15) * 16);
  __syncthreads();

  f4 acc[4][4];
#pragma unroll
  for (int i = 0; i < 4; ++i)
#pragma unroll
    for (int nt = 0; nt < 4; ++nt) {
      const float bv = bias[nt];
      acc[i][nt] = f4{bv, bv, bv, bv};
    }
#pragma unroll
  for (int i = 0; i < 4; ++i)
#pragma unroll
    for (int nt = 0; nt < 4; ++nt)
      acc[i][nt] = __builtin_amdgcn_mfma_f32_16x16x32_bf16(
          afr[i], bfr[nt], acc[i][nt], 0, 0, 0);

  short* po = (short*)smem;
  float wsum[4] = {0.f, 0.f, 0.f, 0.f};
#pragma unroll
  for (int i = 0; i < 4; ++i)
#pragma unroll
    for (int nt = 0; nt < 4; ++nt) {
      const f4 v = acc[i][nt];
#pragma unroll
      for (int r = 0; r < 4; ++r) {
        float x = v[r] > 0.f ? v[r] : 0.f;
        wsum[nt] += x;
        po[(w * 64 + i * 16 + oct * 4 + r) * 72 + nt * 16 + ln15] = f2bf(x);
      }
    }
#pragma unroll
  for (int nt = 0; nt < 4; ++nt) {
    float s = wsum[nt];
    s += __shfl_xor(s, 16);
    s += __shfl_xor(s, 32);
    if (l < 16) wred[(nt * 16 + ln15) * 4 + w] = s;
  }
  __syncthreads();

  {
    const int4* src = reinterpret_cast<const int4*>(smem + t * 144);
    int4* dst = reinterpret_cast<int4*>(x1) +
                ((size_t)b * 1024 + quarter * 256 + t) * 8;
#pragma unroll
    for (int j = 0; j < 8; ++j) dst[j] = src[j];
  }
  if (t < 64) {
    const float s = wred[t * 4] + wred[t * 4 + 1] + wred[t * 4 + 2] + wred[t * 4 + 3];
    part2[((size_t)quarter * 64 + t) * 128 + b] = s;
  }
}

// ---------------- K2: selection (redundant per block) + weight prep (block j) -----
__global__ __launch_bounds__(256) void k2_selprep(
    const float* __restrict__ part2, const float* __restrict__ gate_w,
    const float* __restrict__ w2, const float* __restrict__ b2,
    int* __restrict__ sel, unsigned short* __restrict__ w2t,
    float* __restrict__ b2s) {
  const int t = threadIdx.x;
  const int j = blockIdx.x;  // slot = rank
  __shared__ float gw[256 * 65];
  __shared__ float red[64 * 33];
  __shared__ float sig[64];
  __shared__ float sc[256];
  __shared__ int pick;

  {  // stage gate_w coalesced into padded LDS
    const float4* gv = reinterpret_cast<const float4*>(gate_w);
#pragma unroll
    for (int i = 0; i < 16; ++i) {
      const int f = i * 256 + t;
      const float4 v = gv[f];
      float* d = &gw[(f >> 4) * 65 + (f & 15) * 4];
      d[0] = v.x; d[1] = v.y; d[2] = v.z; d[3] = v.w;
    }
  }

  float prt[8];
#pragma unroll
  for (int k = 0; k < 8; ++k) prt[k] = 0.f;
  const float4* pv = reinterpret_cast<const float4*>(part2);
#pragma unroll
  for (int q = 0; q < 32; ++q) {
    const float4 v = pv[q * 256 + t];
    prt[q & 7] += v.x + v.y + v.z + v.w;
  }
#pragma unroll
  for (int k = 0; k < 8; ++k)
    red[(k * 8 + (t >> 5)) * 33 + (t & 31)] = prt[k];
  __syncthreads();
  if (t < 64) {
    float s = 0.f;
    for (int i = 0; i < 32; ++i) s += red[t * 33 + i];
    sig[t] = s * (1.0f / 131072.0f);
  }
  __syncthreads();

  {
    float lg = 0.f;
#pragma unroll 8
    for (int i = 0; i < 64; ++i) lg += gw[t * 65 + i] * sig[i];
    sc[t] = lg;  // softplus monotone -> rank by logits
  }
  __syncthreads();

  {
    const float v = sc[t];
    int r = 0;
    for (int i = 0; i < 256; ++i) {
      const float vi = sc[i];
      r += (vi > v) || (vi == v && i < t);
    }
    if (r == j) pick = t;
    if (j == 0 && r < NSEL) sel[r] = t;
  }
  __syncthreads();

  const int c = pick;
  if (t == 0) b2s[j] = b2[c];
  for (int id = t; id < 576; id += 256) {
    const float v = w2[(size_t)c * 576 + id];
    const int ic = id / 9;
    const int s = id - ic * 9;
    w2t[((size_t)s * 48 + j) * 64 + ic] = f2bf(v);
  }
}

// ---------------- K3: conv2 via 9-shift bf16 MFMA + bias + ReLU + maxpool ---------
__global__ __launch_bounds__(256) void k3_conv2(
    const unsigned short* __restrict__ x1, const unsigned short* __restrict__ w2t,
    const float* __restrict__ b2s, unsigned short* __restrict__ pooledt) {
  const int b = blockIdx.x, quarter = blockIdx.y;
  const int t = threadIdx.x;
  const int w = t >> 6, l = t & 63;
  const int q4 = l >> 4, ln15 = l & 15;
  __shared__ short xt[20480];

  const int r0 = quarter * 8;

  for (int q = 0; q < 10; ++q) {
    const int S = (w * 10 + q) * 64 + l;
    const int pix = S >> 3, slot = S & 7;
    const int row = pix >> 5, col = pix & 31;
    int gr = r0 - 1 + row;
    gr = gr < 0 ? 0 : (gr > 31 ? 31 : gr);
    const unsigned short* gsrc =
        x1 + ((size_t)(b * 1024 + gr * 32 + col) * 64) + (slot ^ (pix & 7)) * 8;
    gl_lds16((const void*)gsrc, (void*)&xt[(w * 10 + q) * 512]);
  }
  __syncthreads();

  f4 acc[4][3];
  const f4 fz = {0.f, 0.f, 0.f, 0.f};
#pragma unroll
  for (int i = 0; i < 4; ++i)
#pragma unroll
    for (int nt = 0; nt < 3; ++nt) acc[i][nt] = fz;

  const int w4 = w * 4;
  const sh8 zz = {0, 0, 0, 0, 0, 0, 0, 0};

#pragma unroll
  for (int kh = 0; kh < 3; ++kh)
#pragma unroll
    for (int kw = 0; kw < 3; ++kw) {
      const int sh = kh * 3 + kw;
      sh8 bf[3][2];
#pragma unroll
      for (int nt = 0; nt < 3; ++nt)
#pragma unroll
        for (int ks = 0; ks < 2; ++ks)
          bf[nt][ks] = *reinterpret_cast<const sh8*>(
              w2t + ((size_t)(sh * 48 + nt * 16 + ln15) * 64 + ks * 32 + q4 * 8));
#pragma unroll
      for (int i = 0; i < 4; ++i) {
        const int mt = w4 + i;
        const int lsr = (mt >> 1) + kh;
        const int gsr = r0 + lsr - 1;
        if ((unsigned)gsr < 32u) {
          const int w_ = (mt & 1) * 16 + ln15;
          const int cc = w_ + kw - 1;
          const bool cv = (unsigned)cc < 32u;
          int p = lsr * 32 + cc;
          p = p < 0 ? 0 : (p > 319 ? 319 : p);
#pragma unroll
          for (int ks = 0; ks < 2; ++ks) {
            sh8 af = *reinterpret_cast<const sh8*>(
                &xt[p * 64 + (((ks << 2) | q4) ^ (p & 7)) * 8]);
            af = cv ? af : zz;
            acc[i][0] = __builtin_amdgcn_mfma_f32_16x16x32_bf16(af, bf[0][ks], acc[i][0], 0, 0, 0);
            acc[i][1] = __builtin_amdgcn_mfma_f32_16x16x32_bf16(af, bf[1][ks], acc[i][1], 0, 0, 0);
            acc[i][2] = __builtin_amdgcn_mfma_f32_16x16x32_bf16(af, bf[2][ks], acc[i][2], 0, 0, 0);
          }
        }
      }
    }

  __syncthreads();

  float bias[3];
#pragma unroll
  for (int nt = 0; nt < 3; ++nt) bias[nt] = b2s[nt * 16 + ln15];

  unsigned short* ps = reinterpret_cast<unsigned short*>(xt);
#pragma unroll
  for (int a = 0; a < 2; ++a) {
#pragma unroll
    for (int nt = 0; nt < 3; ++nt) {
      const f4 A = acc[a][nt], Bv = acc[a + 2][nt];
#pragma unroll
      for (int pr = 0; pr < 2; ++pr) {
        float m = fmaxf(fmaxf(A[pr * 2], A[pr * 2 + 1]),
                        fmaxf(Bv[pr * 2], Bv[pr * 2 + 1]));
        m = fmaxf(m + bias[nt], 0.f);
        const int pl = w * 16 + a * 8 + q4 * 2 + pr;
        ps[(nt * 16 + ln15) * 64 + pl] = f2bf(m);
      }
    }
  }
  __syncthreads();

  const int4* psv = reinterpret_cast<const int4*>(xt);
  int4* po = reinterpret_cast<int4*>(pooledt);
  for (int c = t; c < 384; c += 256) {
    const int j = c >> 3, sub = c & 7;
    po[(size_t)(j * 32 + quarter * 8 + sub) * 128 + b] = psv[c];
  }
}

// ---------------- K4: bf16 MFMA GEMM partials. BM=128, BN=32, Ksplit=32 -----------
__global__ __launch_bounds__(256) void k4_fc(
    const unsigned short* __restrict__ pooledt, const float* __restrict__ fc_w,
    const int* __restrict__ sel, unsigned short* __restrict__ fcpart) {
  const int ntile = blockIdx.x;  // 0..31  (BN=32)
  const int ks = blockIdx.y;     // 0..31  (K chunk = 384)
  const int t = threadIdx.x;
  const int w = t >> 6, l = t & 63;
  const int ln15 = l & 15;

  __shared__ short Ab[2][8192];       // [ko 8][m 128][8]
  __shared__ short Bb[2][8 * 33 * 8]; // [ko 8][n pad33][8]

  f4 acc00 = {0.f, 0.f, 0.f, 0.f}, acc01 = acc00, acc10 = acc00, acc11 = acc00;

  int chs[6];
#pragma unroll
  for (int i = 0; i < 6; ++i)
    chs[i] = __builtin_amdgcn_readfirstlane(sel[(ks * 6 + i) >> 2]);

  const int n0 = ntile * 32;
  const int bn = w * 8 + (l >> 3);      // B row 0..31
  int ngb = n0 + bn; if (ngb > 999) ngb = 999;  // tail cols ignored by k5
  const float* brow = fc_w + (size_t)ngb * 65536 + (l & 7) * 8;

  const int4* pt = reinterpret_cast<const int4*>(pooledt);
  const int kb0 = ks * 48;

  int4 av[4];
  float4 bv0, bv1;

#define LOADAB(tn)                                                        \
  {                                                                       \
    _Pragma("unroll") for (int it = 0; it < 4; ++it) {                    \
      const int s = it * 256 + t;                                         \
      av[it] = pt[(kb0 + (tn) * 8 + (s >> 7)) * 128 + (s & 127)];         \
    }                                                                     \
    const float* bp = brow + chs[tn] * 256 + ((ks * 6 + (tn)) & 3) * 64;  \
    bv0 = *reinterpret_cast<const float4*>(bp);                           \
    bv1 = *reinterpret_cast<const float4*>(bp + 4);                       \
  }
#define WRITEAB(buf)                                                      \
  {                                                                       \
    _Pragma("unroll") for (int it = 0; it < 4; ++it)                      \
      *reinterpret_cast<int4*>(&Ab[buf][(it * 256 + t) * 8]) = av[it];    \
    int4 bw;                                                              \
    bw.x = f2bf(bv0.x) | ((unsigned)f2bf(bv0.y) << 16);                   \
    bw.y = f2bf(bv0.z) | ((unsigned)f2bf(bv0.w) << 16);                   \
    bw.z = f2bf(bv1.x) | ((unsigned)f2bf(bv1.y) << 16);                   \
    bw.w = f2bf(bv1.z) | ((unsigned)f2bf(bv1.w) << 16);                   \
    *reinterpret_cast<int4*>(&Bb[buf][((l & 7) * 33 + bn) * 8]) = bw;     \
  }

  LOADAB(0);
  WRITEAB(0);
  __syncthreads();

  for (int tt = 0; tt < 6; ++tt) {
    const int cur = tt & 1, nxt = cur ^ 1;
    if (tt < 5) LOADAB(tt + 1);

#pragma unroll
    for (int s2 = 0; s2 < 2; ++s2) {
      const int kg = s2 * 4 + (l >> 4);
      const int m0 = w * 32 + ln15;
      sh8 a0 = *reinterpret_cast<const sh8*>(&Ab[cur][(kg * 128 + m0) * 8]);
      sh8 a1 = *reinterpret_cast<const sh8*>(&Ab[cur][(kg * 128 + m0 + 16) * 8]);
      sh8 b0 = *reinterpret_cast<const sh8*>(&Bb[cur][(kg * 33 + ln15) * 8]);
      sh8 b1 = *reinterpret_cast<const sh8*>(&Bb[cur][(kg * 33 + 16 + ln15) * 8]);
      acc00 = __builtin_amdgcn_mfma_f32_16x16x32_bf16(a0, b0, acc00, 0, 0, 0);
      acc01 = __builtin_amdgcn_mfma_f32_16x16x32_bf16(a0, b1, acc01, 0, 0, 0);
      acc10 = __builtin_amdgcn_mfma_f32_16x16x32_bf16(a1, b0, acc10, 0, 0, 0);
      acc11 = __builtin_amdgcn_mfma_f32_16x16x32_bf16(a1, b1, acc11, 0, 0, 0);
    }

    if (tt < 5) WRITEAB(nxt);
    __syncthreads();
  }
#undef LOADAB
#undef WRITEAB

  const int r0 = (l >> 4) * 4;
#pragma unroll
  for (int fm = 0; fm < 2; ++fm)
#pragma unroll
    for (int fn = 0; fn < 2; ++fn) {
      const f4 a = fm == 0 ? (fn == 0 ? acc00 : acc01) : (fn == 0 ? acc10 : acc11);
#pragma unroll
      for (int r = 0; r < 4; ++r) {
        const int m = w * 32 + fm * 16 + r0 + r;
        const int nc = n0 + fn * 16 + ln15;
        fcpart[(((size_t)ks * 128 + m) << 10) + nc] = f2bf(a[r]);
      }
    }
}

// ---------------- K5: reduce 32 bf16 K-split partials + bias ----------------------
__global__ __launch_bounds__(256) void k5_reduce(
    const unsigned short* __restrict__ fcpart, const float* __restrict__ fc_b,
    float* __restrict__ out) {
  const int id = blockIdx.x * 256 + threadIdx.x;  // 0..127999
  const int b = id / 1000;
  const int n = id - b * 1000;
  float s = fc_b[n];
#pragma unroll
  for (int ks = 0; ks < 32; ++ks)
    s += bf2f(fcpart[(((size_t)ks * 128 + b) << 10) + n]);
  out[id] = s;
}

extern "C" void kernel_launch(void* const* d_in, const int* in_sizes, int n_in,
                              void* d_out, int out_size, void* d_ws, size_t ws_size,
                              hipStream_t stream) {
  (void)in_sizes; (void)n_in; (void)out_size; (void)ws_size;
  const float* x0     = (const float*)d_in[0];
  const float* w1     = (const float*)d_in[1];
  const float* b1     = (const float*)d_in[2];
  const float* gate_w = (const float*)d_in[3];
  const float* w2     = (const float*)d_in[4];
  const float* b2     = (const float*)d_in[5];
  const float* fc_w   = (const float*)d_in[6];
  const float* fc_b   = (const float*)d_in[7];
  float* out = (float*)d_out;

  char* ws = (char*)d_ws;
  unsigned short* x1      = (unsigned short*)(ws);             // 16,777,216 B
  unsigned short* pooledt = (unsigned short*)(ws + 16777216);  //  3,145,728 B
  float*          part2   = (float*)(ws + 19922944);           //    131,072 B
  int*            sel     = (int*)  (ws + 20054016);           //        256 B
  unsigned short* w2t     = (unsigned short*)(ws + 20054272);  //     55,296 B
  float*          b2s     = (float*)(ws + 20109568);           //        768 B
  unsigned short* fcpart  = (unsigned short*)(ws + 20110336);  //  8,388,608 B

  hipLaunchKernelGGL(k1_conv1, dim3(128, 4), dim3(256), 0, stream, x0, w1, b1, x1, part2);
  hipLaunchKernelGGL(k2_selprep, dim3(48), dim3(256), 0, stream, part2, gate_w, w2, b2, sel, w2t, b2s);
  hipLaunchKernelGGL(k3_conv2, dim3(128, 4), dim3(256), 0, stream, x1, w2t, b2s, pooledt);
  hipLaunchKernelGGL(k4_fc, dim3(32, 32), dim3(256), 0, stream, pooledt, fc_w, sel, fcpart);
  hipLaunchKernelGGL(k5_reduce, dim3(500), dim3(256), 0, stream, fcpart, fc_b, out);
}